// Round 7
// baseline (438.989 us; speedup 1.0000x reference)
//
#include <hip/hip_runtime.h>
#include <hip/hip_bf16.h>

#define BS 2
#define QLEN 2048
#define DIM 2048
#define H 16
#define DH 128
#define MTOT (BS*QLEN)

typedef __hip_bfloat16 bf16;
using f32x4 = __attribute__((ext_vector_type(4))) float;
using s16x8 = __attribute__((ext_vector_type(8))) short;

__device__ inline void gload_lds16(const bf16* g, bf16* l) {
    __builtin_amdgcn_global_load_lds(
        (const __attribute__((address_space(1))) void*)g,
        (__attribute__((address_space(3))) void*)l,
        16, 0, 0);
}

// ---------------- fp32 -> bf16 cast: 6 slices in one dispatch ----------------
__global__ __launch_bounds__(256) void cast6(
    const float* __restrict__ x,
    const float* __restrict__ w0, const float* __restrict__ w1,
    const float* __restrict__ w2, const float* __restrict__ w3,
    bf16* xo, bf16* o0, bf16* o1, bf16* o2, bf16* o3, int n4)
{
    const float* in; bf16* out;
    switch (blockIdx.y) {
        case 0:  in = w0; out = o0; break;
        case 1:  in = w1; out = o1; break;
        case 2:  in = w2; out = o2; break;
        case 3:  in = w3; out = o3; break;
        case 4:  in = x;        out = xo;        break;
        default: in = x + 4*(size_t)n4; out = xo + 4*(size_t)n4; break;
    }
    int i = blockIdx.x * 256 + threadIdx.x;
    if (i < n4) {
        float4 v = ((const float4*)in)[i];
        __hip_bfloat162 p0 = __float22bfloat162_rn(make_float2(v.x, v.y));
        __hip_bfloat162 p1 = __float22bfloat162_rn(make_float2(v.z, v.w));
        ((__hip_bfloat162*)out)[2*i]   = p0;
        ((__hip_bfloat162*)out)[2*i+1] = p1;
    }
}

// ---------------- fused Q/K/V projection GEMM, BK=64, source-swizzled LDS ----------------
// C = (A * W^T + bias) * scale.  z=0: Q (scaled). z=1: K. z=2: V transposed
// out[(b*DIM + n)*QLEN + q].
// LDS rows stride 64 elem; slot g of row r holds global chunk g^(r&7)
// (swizzle applied to SOURCE address — global_load_lds dest is lane-ordered, m104/m108).
__global__ __launch_bounds__(256) void gemm_qkv(
    const bf16* __restrict__ A,
    const bf16* __restrict__ Wq, const bf16* __restrict__ Wk, const bf16* __restrict__ Wv,
    const float* __restrict__ bq, const float* __restrict__ bk, const float* __restrict__ bv,
    bf16* __restrict__ Qo, bf16* __restrict__ Ko, bf16* __restrict__ Vo,
    float qscale)
{
    __shared__ __align__(16) bf16 smem[128*136];   // As[128*64] @0, Bs @8192; Ts overlay
    bf16* As = smem;
    bf16* Bs = smem + 128*64;

    const int z = blockIdx.z;
    const bf16*  B    = (z == 0) ? Wq : (z == 1) ? Wk : Wv;
    const float* bias = (z == 0) ? bq : (z == 1) ? bk : bv;
    const float  scale = (z == 0) ? qscale : 1.0f;

    const int t = threadIdx.x;
    const int lane = t & 63, w = t >> 6;
    const int row16 = lane & 15, quad = lane >> 4;
    const int m0 = blockIdx.y * 128, n0 = blockIdx.x * 128;
    const int mo = (w >> 1) * 64, no = (w & 1) * 64;

    f32x4 acc[4][4];
    for (int i = 0; i < 4; i++)
        for (int j = 0; j < 4; j++)
            acc[i][j] = (f32x4){0.f, 0.f, 0.f, 0.f};

    for (int kt = 0; kt < DIM; kt += 64) {
        __syncthreads();
        #pragma unroll
        for (int i = 0; i < 4; i++) {
            int idx = i*256 + t;              // LDS dest = base + lane*16
            int row = idx >> 3, g = idx & 7;
            int src = g ^ (row & 7);          // source-side XOR swizzle
            gload_lds16(A + (size_t)(m0 + row) * DIM + kt + src*8, &As[idx*8]);
            gload_lds16(B + (size_t)(n0 + row) * DIM + kt + src*8, &Bs[idx*8]);
        }
        __syncthreads();

        #pragma unroll
        for (int kh = 0; kh < 2; kh++) {
            s16x8 af[4], bfr[4];
            #pragma unroll
            for (int mt = 0; mt < 4; mt++)
                af[mt] = *(const s16x8*)&As[(mo + mt*16 + row16)*64 + (((kh*4+quad) ^ (row16&7)))*8];
            #pragma unroll
            for (int nt = 0; nt < 4; nt++)
                bfr[nt] = *(const s16x8*)&Bs[(no + nt*16 + row16)*64 + (((kh*4+quad) ^ (row16&7)))*8];
            #pragma unroll
            for (int mt = 0; mt < 4; mt++)
                #pragma unroll
                for (int nt = 0; nt < 4; nt++)
                    acc[mt][nt] = __builtin_amdgcn_mfma_f32_16x16x32_bf16(
                        af[mt], bfr[nt], acc[mt][nt], 0, 0, 0);
        }
    }

    if (z < 2) {
        bf16* out = (z == 0) ? Qo : Ko;
        for (int mt = 0; mt < 4; mt++)
            for (int nt = 0; nt < 4; nt++) {
                int n = n0 + no + nt*16 + row16;
                float bv_ = bias[n];
                for (int r = 0; r < 4; r++) {
                    int m = m0 + mo + mt*16 + quad*4 + r;
                    out[(size_t)m * DIM + n] = __float2bfloat16((acc[mt][nt][r] + bv_) * scale);
                }
            }
    } else {
        __syncthreads();                 // As/Bs dead for ALL waves before Ts reuse
        bf16* Ts = smem;                 // 128*136
        for (int mt = 0; mt < 4; mt++)
            for (int nt = 0; nt < 4; nt++) {
                int nn = no + nt*16 + row16;
                float bv_ = bias[n0 + nn];
                for (int r = 0; r < 4; r++) {
                    int mm = mo + mt*16 + quad*4 + r;
                    Ts[nn*136 + mm] = __float2bfloat16(acc[mt][nt][r] + bv_);
                }
            }
        __syncthreads();
        const int b = m0 >> 11, q0b = m0 & 2047;
        for (int i = 0; i < 8; i++) {
            int chunk = t + i*256;
            int row = chunk >> 4;
            int c16 = chunk & 15;
            s16x8 val = *(const s16x8*)&Ts[row*136 + c16*8];
            *(s16x8*)(Vo + ((size_t)(b*DIM + n0 + row))*QLEN + q0b + c16*8) = val;
        }
    }
}

// ---------------- O-projection GEMM: BK=64, source-swizzled, fp32 out ----------------
__global__ __launch_bounds__(256) void gemm_out(
    const bf16* __restrict__ A, const bf16* __restrict__ B,
    const float* __restrict__ bias, float* __restrict__ out)
{
    __shared__ __align__(16) bf16 As[128*64];
    __shared__ __align__(16) bf16 Bs[128*64];

    const int t = threadIdx.x;
    const int lane = t & 63, w = t >> 6;
    const int row16 = lane & 15, quad = lane >> 4;
    const int m0 = blockIdx.y * 128, n0 = blockIdx.x * 128;
    const int mo = (w >> 1) * 64, no = (w & 1) * 64;

    f32x4 acc[4][4];
    for (int i = 0; i < 4; i++)
        for (int j = 0; j < 4; j++)
            acc[i][j] = (f32x4){0.f, 0.f, 0.f, 0.f};

    for (int kt = 0; kt < DIM; kt += 64) {
        __syncthreads();
        #pragma unroll
        for (int i = 0; i < 4; i++) {
            int idx = i*256 + t;
            int row = idx >> 3, g = idx & 7;
            int src = g ^ (row & 7);
            gload_lds16(A + (size_t)(m0 + row) * DIM + kt + src*8, &As[idx*8]);
            gload_lds16(B + (size_t)(n0 + row) * DIM + kt + src*8, &Bs[idx*8]);
        }
        __syncthreads();

        #pragma unroll
        for (int kh = 0; kh < 2; kh++) {
            s16x8 af[4], bfr[4];
            #pragma unroll
            for (int mt = 0; mt < 4; mt++)
                af[mt] = *(const s16x8*)&As[(mo + mt*16 + row16)*64 + (((kh*4+quad) ^ (row16&7)))*8];
            #pragma unroll
            for (int nt = 0; nt < 4; nt++)
                bfr[nt] = *(const s16x8*)&Bs[(no + nt*16 + row16)*64 + (((kh*4+quad) ^ (row16&7)))*8];
            #pragma unroll
            for (int mt = 0; mt < 4; mt++)
                #pragma unroll
                for (int nt = 0; nt < 4; nt++)
                    acc[mt][nt] = __builtin_amdgcn_mfma_f32_16x16x32_bf16(
                        af[mt], bfr[nt], acc[mt][nt], 0, 0, 0);
        }
    }

    for (int mt = 0; mt < 4; mt++)
        for (int nt = 0; nt < 4; nt++) {
            int n = n0 + no + nt*16 + row16;
            float bv_ = bias[n];
            for (int r = 0; r < 4; r++) {
                int m = m0 + mo + mt*16 + quad*4 + r;
                out[(size_t)m * DIM + n] = acc[mt][nt][r] + bv_;
            }
        }
}

// ---------------- flash attention: KT=32, dbuf K+V, ONE barrier/iter, 40 KB LDS ----------------
// Q pre-scaled by log2(e)/sqrt(DH); p = exp2(s - 20); offset cancels in o/l.
// Ks[buf]: 32 rows x 16 chunks, slot c holds global chunk c^(row&15) (source swizzle).
// Vs[buf]: 128 d-rows x 4 chunks, slot c holds chunk c^(d&3) (source swizzle).
// Pl: per-wave 32 rows x 4 chunks (stride 32), chunk c at slot c^((row>>2)&3) (ds_write).
__global__ __launch_bounds__(256, 3) void attn(
    const bf16* __restrict__ Q, const bf16* __restrict__ Kb,
    const bf16* __restrict__ Vt, const int* __restrict__ mask,
    bf16* __restrict__ Ctx)
{
    __shared__ __align__(16) bf16 Ks[2][32*128];  // 16 KB
    __shared__ __align__(16) bf16 Vs[2][128*32];  // 16 KB
    __shared__ __align__(16) bf16 Pl[4][32*32];   // 8 KB

    const int t = threadIdx.x, w = t >> 6, lane = t & 63;
    const int row16 = lane & 15, quad = lane >> 4;
    const int bh = blockIdx.y, b = bh >> 4, h = bh & 15;
    const int q0 = blockIdx.x * 128 + w * 32;

    s16x8 qf[2][4];
    for (int qs = 0; qs < 2; qs++) {
        const bf16* qp = Q + (size_t)(b*QLEN + q0 + qs*16 + row16) * DIM + h*DH;
        for (int ks = 0; ks < 4; ks++)
            qf[qs][ks] = *(const s16x8*)(qp + ks*32 + quad*8);
    }

    f32x4 o[2][8];
    for (int qs = 0; qs < 2; qs++)
        for (int i = 0; i < 8; i++) o[qs][i] = (f32x4){0.f, 0.f, 0.f, 0.f};
    float lsum[2][4] = {{0.f,0.f,0.f,0.f},{0.f,0.f,0.f,0.f}};
    const int* mrow = mask + b * QLEN;

    const bf16* Kbase = Kb + (size_t)b*QLEN*DIM + h*DH;
    const bf16* Vbase = Vt + ((size_t)b*DIM + h*DH) * QLEN;

    // prologue: tile 0 into buf 0 (2 K-chunks + 2 V-chunks per thread)
    #pragma unroll
    for (int i = 0; i < 2; i++) {
        int idx = i*256 + t;                  // 0..511
        int kr = idx >> 4, kc = idx & 15;
        gload_lds16(Kbase + (size_t)kr * DIM + ((kc ^ (kr & 15)))*8, &Ks[0][idx*8]);
        int vd = idx >> 2, vc = idx & 3;
        gload_lds16(Vbase + (size_t)vd * QLEN + ((vc ^ (vd & 3)))*8, &Vs[0][idx*8]);
    }

    for (int it = 0; it < QLEN/32; it++) {
        const int kt = it * 32, buf = it & 1;
        __syncthreads();   // single barrier: drains DMA(it) AND protects buf^1 for reuse

        // prefetch tile it+1 into buf^1 — covered by the full compute phase below
        if (it + 1 < QLEN/32) {
            const int kt2 = kt + 32;
            #pragma unroll
            for (int i = 0; i < 2; i++) {
                int idx = i*256 + t;
                int kr = idx >> 4, kc = idx & 15;
                gload_lds16(Kbase + (size_t)(kt2 + kr) * DIM + ((kc ^ (kr & 15)))*8,
                            &Ks[buf^1][idx*8]);
                int vd = idx >> 2, vc = idx & 3;
                gload_lds16(Vbase + (size_t)vd * QLEN + kt2 + ((vc ^ (vd & 3)))*8,
                            &Vs[buf^1][idx*8]);
            }
        }

        float mval[2];
        #pragma unroll
        for (int nt = 0; nt < 2; nt++)
            mval[nt] = (mrow[kt + nt*16 + row16] != 0) ? -20.0f : -1e30f;

        // ---- scores: 32 q-rows x 32 k-cols from Ks[buf] ----
        f32x4 sc[2][2];
        for (int qs = 0; qs < 2; qs++)
            for (int nt = 0; nt < 2; nt++) sc[qs][nt] = (f32x4){0.f, 0.f, 0.f, 0.f};
        #pragma unroll
        for (int ks = 0; ks < 4; ks++) {
            #pragma unroll
            for (int nt = 0; nt < 2; nt++) {
                int rrow = nt*16 + row16;
                int slot = (ks*4 + quad) ^ (rrow & 15);
                s16x8 kf = *(const s16x8*)&Ks[buf][rrow*128 + slot*8];
                sc[0][nt] = __builtin_amdgcn_mfma_f32_16x16x32_bf16(qf[0][ks], kf, sc[0][nt], 0, 0, 0);
                sc[1][nt] = __builtin_amdgcn_mfma_f32_16x16x32_bf16(qf[1][ks], kf, sc[1][nt], 0, 0, 0);
            }
        }

        // ---- softmax numerator: p = exp2(s - 20) -> Pl (swizzled) ----
        #pragma unroll
        for (int qs = 0; qs < 2; qs++) {
            #pragma unroll
            for (int r = 0; r < 4; r++) {
                int prow = qs*16 + quad*4 + r;
                int swz = (qs*4 + quad) & 3;          // (prow>>2)&3
                float ts = 0.f;
                #pragma unroll
                for (int nt = 0; nt < 2; nt++) {
                    float p = exp2f(sc[qs][nt][r] + mval[nt]);
                    ts += p;
                    int chunk = nt*2 + (row16 >> 3);
                    int slot = chunk ^ swz;
                    Pl[w][prow*32 + slot*8 + (row16 & 7)] = __float2bfloat16(p);
                }
                lsum[qs][r] += ts;
            }
        }

        // ---- PV from Vs[buf] (same-wave Pl ordering handled by lgkmcnt) ----
        {
            int ps0 = quad ^ ((0*4 + (row16 >> 2)) & 3);
            int ps1 = quad ^ ((1*4 + (row16 >> 2)) & 3);
            s16x8 pf0 = *(const s16x8*)&Pl[w][(0*16 + row16)*32 + ps0*8];
            s16x8 pf1 = *(const s16x8*)&Pl[w][(1*16 + row16)*32 + ps1*8];
            #pragma unroll
            for (int nt = 0; nt < 8; nt++) {
                int d = nt*16 + row16;
                int vslot = quad ^ (d & 3);
                s16x8 vf = *(const s16x8*)&Vs[buf][d*32 + vslot*8];
                o[0][nt] = __builtin_amdgcn_mfma_f32_16x16x32_bf16(pf0, vf, o[0][nt], 0, 0, 0);
                o[1][nt] = __builtin_amdgcn_mfma_f32_16x16x32_bf16(pf1, vf, o[1][nt], 0, 0, 0);
            }
        }
    }

    for (int qs = 0; qs < 2; qs++) {
        float inv[4];
        for (int r = 0; r < 4; r++) {
            float ts = lsum[qs][r];
            ts += __shfl_xor(ts, 1);
            ts += __shfl_xor(ts, 2);
            ts += __shfl_xor(ts, 4);
            ts += __shfl_xor(ts, 8);
            inv[r] = 1.0f / ts;
        }
        for (int nt = 0; nt < 8; nt++)
            for (int r = 0; r < 4; r++) {
                float v = o[qs][nt][r] * inv[r];
                Ctx[(size_t)(b*QLEN + q0 + qs*16 + quad*4 + r) * DIM + h*DH + nt*16 + row16] =
                    __float2bfloat16(v);
            }
    }
}

extern "C" void kernel_launch(void* const* d_in, const int* in_sizes, int n_in,
                              void* d_out, int out_size, void* d_ws, size_t ws_size,
                              hipStream_t stream) {
    const float* x    = (const float*)d_in[0];
    const int*   mask = (const int*)d_in[1];
    const float* wq   = (const float*)d_in[2];
    const float* bq   = (const float*)d_in[3];
    const float* wk   = (const float*)d_in[4];
    const float* bk   = (const float*)d_in[5];
    const float* wv   = (const float*)d_in[6];
    const float* bv   = (const float*)d_in[7];
    const float* wo   = (const float*)d_in[8];
    const float* bo   = (const float*)d_in[9];

    char* ws = (char*)d_ws;
    const size_t MB = 1024 * 1024;
    bf16* Xb  = (bf16*)(ws);             // 16MB, later reused as Ctx
    bf16* Qb  = (bf16*)(ws + 16*MB);
    bf16* Kb  = (bf16*)(ws + 32*MB);
    bf16* Vtb = (bf16*)(ws + 48*MB);
    bf16* Wqb = (bf16*)(ws + 64*MB);
    bf16* Wkb = (bf16*)(ws + 72*MB);
    bf16* Wvb = (bf16*)(ws + 80*MB);
    bf16* Wob = (bf16*)(ws + 88*MB);
    bf16* Ctx = Xb;

    int n4w = (DIM*DIM) / 4;             // 1,048,576 float4s per weight / per x-half
    cast6<<<dim3(n4w/256, 6), 256, 0, stream>>>(x, wq, wk, wv, wo,
                                                Xb, Wqb, Wkb, Wvb, Wob, n4w);

    const float qscale = 0.08838834764831845f * 1.4426950408889634f;  // 1/sqrt(128)*log2(e)
    gemm_qkv<<<dim3(DIM/128, MTOT/128, 3), 256, 0, stream>>>(
        Xb, Wqb, Wkb, Wvb, bq, bk, bv, Qb, Kb, Vtb, qscale);

    attn<<<dim3(QLEN/128, BS*H), 256, 0, stream>>>(Qb, Kb, Vtb, mask, Ctx);

    gemm_out<<<dim3(DIM/128, MTOT/128), 256, 0, stream>>>(Ctx, Wob, bo, (float*)d_out);
}